// Round 2
// baseline (689.881 us; speedup 1.0000x reference)
//
#include <hip/hip_runtime.h>

#define NUM_BONES  50
#define FEAT       150
#define FRAMES_PER_BLOCK 32
#define THREADS    256
#define TILE_ELEMS (FRAMES_PER_BLOCK * FEAT)   // 4800 floats per tensor
#define N4         (TILE_ELEMS / 4)            // 1200 float4s
#define NLOAD      5                           // ceil(1200/256)
#define TINY_F     1.17549435e-38f             // np.finfo(float32).tiny
#define GRID_BLOCKS ((64 * 4096) / FRAMES_PER_BLOCK)  // 8192

// 50-bone skeleton (body + two 21-bone hands + pad bone (0,2))
__device__ __constant__ int c_ba[NUM_BONES] = {
    0, 1, 2, 3, 1, 5, 6,
    7, 8, 9, 10, 11, 8, 13, 14, 15, 8, 17, 18, 19,
    8, 21, 22, 23, 8, 25, 26, 27,
    4, 29, 30, 31, 32, 29, 34, 35, 36, 29, 38, 39, 40,
    29, 42, 43, 44, 29, 46, 47, 48,
    0
};
__device__ __constant__ int c_bb[NUM_BONES] = {
    1, 2, 3, 4, 5, 6, 7,
    8, 9, 10, 11, 12, 13, 14, 15, 16, 17, 18, 19, 20,
    21, 22, 23, 24, 25, 26, 27, 28,
    29, 30, 31, 32, 33, 34, 35, 36, 37, 38, 39, 40, 41,
    42, 43, 44, 45, 46, 47, 48, 49,
    2
};

__global__ __launch_bounds__(THREADS)
void loss_main(const float* __restrict__ preds,
               const float* __restrict__ targets,
               double* __restrict__ sums,     // [0]=l1, [1]=mse
               int* __restrict__ counter,
               float* __restrict__ out)
{
    __shared__ float s_pm[TILE_ELEMS];
    __shared__ float s_tm[TILE_ELEMS];

    const int tid = threadIdx.x;
    const long long base = (long long)blockIdx.x * TILE_ELEMS;
    const float4* p4 = (const float4*)(preds + base);
    const float4* t4 = (const float4*)(targets + base);
    float4* spm4 = (float4*)s_pm;
    float4* stm4 = (float4*)s_tm;

    // ---- Phase 1a: issue ALL global loads up front (independent, hoisted).
    // Address clamp (not a branch) keeps every load unconditional so the
    // compiler emits 10 back-to-back global_load_dwordx4 per thread.
    float4 pr[NLOAD], tr[NLOAD];
#pragma unroll
    for (int k = 0; k < NLOAD; ++k) {
        int i = tid + k * THREADS;
        int ic = (i < N4) ? i : (N4 - 1);
        pr[k] = p4[ic];
        tr[k] = t4[ic];
    }

    // ---- Phase 1b: mask, L1 term, stage to LDS ----
    float l1 = 0.0f;
#pragma unroll
    for (int k = 0; k < NLOAD; ++k) {
        int i = tid + k * THREADS;
        if (i < N4) {
            float4 p = pr[k];
            float4 t = tr[k];
            float4 pm, tm;
            pm.x = (t.x != 0.0f) ? p.x : 0.0f;  tm.x = t.x;
            pm.y = (t.y != 0.0f) ? p.y : 0.0f;  tm.y = t.y;
            pm.z = (t.z != 0.0f) ? p.z : 0.0f;  tm.z = t.z;
            pm.w = (t.w != 0.0f) ? p.w : 0.0f;  tm.w = t.w;
            // tm == t whenever t != 0; where t == 0, tm is 0 too, so tm = t always.
            l1 += fabsf(pm.x - tm.x) + fabsf(pm.y - tm.y)
                + fabsf(pm.z - tm.z) + fabsf(pm.w - tm.w);
            spm4[i] = pm;
            stm4[i] = tm;
        }
    }
    __syncthreads();

    // ---- Phase 2: bone directions + masked MSE term ----
    float mse = 0.0f;
    const int ntask = FRAMES_PER_BLOCK * NUM_BONES;  // 1600
#pragma unroll 2
    for (int i = tid; i < ntask; i += THREADS) {
        const int f = i / NUM_BONES;
        const int b = i - f * NUM_BONES;
        const float* pm = s_pm + f * FEAT;
        const float* tm = s_tm + f * FEAT;
        const int ja = 3 * c_ba[b];
        const int jb = 3 * c_bb[b];

        float dpx = pm[ja]     - pm[jb];
        float dpy = pm[ja + 1] - pm[jb + 1];
        float dpz = pm[ja + 2] - pm[jb + 2];
        float dtx = tm[ja]     - tm[jb];
        float dty = tm[ja + 1] - tm[jb + 1];
        float dtz = tm[ja + 2] - tm[jb + 2];

        float lp = sqrtf(dpx * dpx + dpy * dpy + dpz * dpz);
        float lt = sqrtf(dtx * dtx + dty * dty + dtz * dtz);
        float ip = 1.0f / (lp + TINY_F);
        float it = 1.0f / (lt + TINY_F);

        const int o = 3 * b;
        float e0 = dpx * ip - dtx * it;
        float e1 = dpy * ip - dty * it;
        float e2 = dpz * ip - dtz * it;
        if (tm[o]     != 0.0f) mse += e0 * e0;
        if (tm[o + 1] != 0.0f) mse += e1 * e1;
        if (tm[o + 2] != 0.0f) mse += e2 * e2;
    }

    // ---- Block reduction (double) ----
    double v0 = (double)l1;
    double v1 = (double)mse;
    for (int off = 32; off > 0; off >>= 1) {
        v0 += __shfl_down(v0, off, 64);
        v1 += __shfl_down(v1, off, 64);
    }
    __shared__ double s_red0[THREADS / 64];
    __shared__ double s_red1[THREADS / 64];
    const int wave = tid >> 6;
    const int lane = tid & 63;
    if (lane == 0) { s_red0[wave] = v0; s_red1[wave] = v1; }
    __syncthreads();
    if (tid == 0) {
        double a = s_red0[0] + s_red0[1] + s_red0[2] + s_red0[3];
        double b = s_red1[0] + s_red1[1] + s_red1[2] + s_red1[3];
        atomicAdd(&sums[0], a);
        atomicAdd(&sums[1], b);
        __threadfence();
        int prev = atomicAdd(counter, 1);
        if (prev == GRID_BLOCKS - 1) {
            // Device-scope atomic reads (RMW +0.0) — coherent across XCDs.
            double s0 = atomicAdd(&sums[0], 0.0);
            double s1 = atomicAdd(&sums[1], 0.0);
            const double N = 64.0 * 4096.0 * 150.0;
            out[0] = (float)(s0 / N + 0.1 * (s1 / N));
        }
    }
}

extern "C" void kernel_launch(void* const* d_in, const int* in_sizes, int n_in,
                              void* d_out, int out_size, void* d_ws, size_t ws_size,
                              hipStream_t stream)
{
    (void)in_sizes; (void)n_in; (void)out_size; (void)ws_size;
    const float* preds   = (const float*)d_in[0];
    const float* targets = (const float*)d_in[1];
    double* sums = (double*)d_ws;
    int* counter = (int*)((char*)d_ws + 2 * sizeof(double));

    hipMemsetAsync(d_ws, 0, 2 * sizeof(double) + sizeof(int), stream);

    loss_main<<<GRID_BLOCKS, THREADS, 0, stream>>>(preds, targets, sums,
                                                   counter, (float*)d_out);
}

// Round 3
// 324.867 us; speedup vs baseline: 2.1236x; 2.1236x over previous
//
#include <hip/hip_runtime.h>

#define NUM_BONES  50
#define FEAT       150
#define FRAMES_PER_BLOCK 32
#define THREADS    256
#define TILE_ELEMS (FRAMES_PER_BLOCK * FEAT)   // 4800 floats per tensor
#define N4         (TILE_ELEMS / 4)            // 1200 float4s
#define NLOAD      5                           // ceil(1200/256)
#define TINY_F     1.17549435e-38f             // np.finfo(float32).tiny
#define TOTAL_TILES      ((64 * 4096) / FRAMES_PER_BLOCK)   // 8192
#define GRID_BLOCKS      1024                               // 4 blocks/CU (LDS-limited)
#define TILES_PER_BLOCK  (TOTAL_TILES / GRID_BLOCKS)        // 8

// 50-bone skeleton (body + two 21-bone hands + pad bone (0,2))
__device__ __constant__ int c_ba[NUM_BONES] = {
    0, 1, 2, 3, 1, 5, 6,
    7, 8, 9, 10, 11, 8, 13, 14, 15, 8, 17, 18, 19,
    8, 21, 22, 23, 8, 25, 26, 27,
    4, 29, 30, 31, 32, 29, 34, 35, 36, 29, 38, 39, 40,
    29, 42, 43, 44, 29, 46, 47, 48,
    0
};
__device__ __constant__ int c_bb[NUM_BONES] = {
    1, 2, 3, 4, 5, 6, 7,
    8, 9, 10, 11, 12, 13, 14, 15, 16, 17, 18, 19, 20,
    21, 22, 23, 24, 25, 26, 27, 28,
    29, 30, 31, 32, 33, 34, 35, 36, 37, 38, 39, 40, 41,
    42, 43, 44, 45, 46, 47, 48, 49,
    2
};

__global__ __launch_bounds__(THREADS)
void loss_main(const float* __restrict__ preds,
               const float* __restrict__ targets,
               double* __restrict__ part0,   // [GRID_BLOCKS] l1 partials
               double* __restrict__ part1)   // [GRID_BLOCKS] mse partials
{
    __shared__ float s_pm[TILE_ELEMS];
    __shared__ float s_tm[TILE_ELEMS];

    const int tid = threadIdx.x;
    float l1  = 0.0f;
    float mse = 0.0f;

    for (int j = 0; j < TILES_PER_BLOCK; ++j) {
        const int tile = blockIdx.x + j * GRID_BLOCKS;
        const long long base = (long long)tile * TILE_ELEMS;
        const float4* p4 = (const float4*)(preds + base);
        const float4* t4 = (const float4*)(targets + base);
        float4* spm4 = (float4*)s_pm;
        float4* stm4 = (float4*)s_tm;

        // ---- Phase 1a: issue all global loads up front (clamp, no branch) ----
        float4 pr[NLOAD], tr[NLOAD];
#pragma unroll
        for (int k = 0; k < NLOAD; ++k) {
            int i = tid + k * THREADS;
            int ic = (i < N4) ? i : (N4 - 1);
            pr[k] = p4[ic];
            tr[k] = t4[ic];
        }

        // ---- Phase 1b: mask, L1 term, stage to LDS ----
#pragma unroll
        for (int k = 0; k < NLOAD; ++k) {
            int i = tid + k * THREADS;
            if (i < N4) {
                float4 p = pr[k];
                float4 t = tr[k];
                float4 pm;
                // tm == t always: where t==0, t*m == 0 == t.
                pm.x = (t.x != 0.0f) ? p.x : 0.0f;
                pm.y = (t.y != 0.0f) ? p.y : 0.0f;
                pm.z = (t.z != 0.0f) ? p.z : 0.0f;
                pm.w = (t.w != 0.0f) ? p.w : 0.0f;
                l1 += fabsf(pm.x - t.x) + fabsf(pm.y - t.y)
                    + fabsf(pm.z - t.z) + fabsf(pm.w - t.w);
                spm4[i] = pm;
                stm4[i] = t;
            }
        }
        __syncthreads();

        // ---- Phase 2: bone directions + masked MSE ----
        // i -> f = i&31 (frame), b = i>>5 (bone): bone index is uniform per
        // half-wave (scalar c_ba/c_bb loads); LDS stride 150 words across
        // lanes = 2-way bank aliasing (free on gfx950).
        const int ntask = FRAMES_PER_BLOCK * NUM_BONES;  // 1600
#pragma unroll
        for (int k = 0; k < 7; ++k) {
            const int i = tid + k * THREADS;
            if (i < ntask) {
                const int f = i & 31;
                const int b = i >> 5;
                const float* pm = s_pm + f * FEAT;
                const float* tm = s_tm + f * FEAT;
                const int ja = 3 * c_ba[b];
                const int jb = 3 * c_bb[b];

                float dpx = pm[ja]     - pm[jb];
                float dpy = pm[ja + 1] - pm[jb + 1];
                float dpz = pm[ja + 2] - pm[jb + 2];
                float dtx = tm[ja]     - tm[jb];
                float dty = tm[ja + 1] - tm[jb + 1];
                float dtz = tm[ja + 2] - tm[jb + 2];

                float lp = sqrtf(dpx * dpx + dpy * dpy + dpz * dpz);
                float lt = sqrtf(dtx * dtx + dty * dty + dtz * dtz);
                float ip = 1.0f / (lp + TINY_F);
                float it = 1.0f / (lt + TINY_F);

                const int o = 3 * b;
                float e0 = dpx * ip - dtx * it;
                float e1 = dpy * ip - dty * it;
                float e2 = dpz * ip - dtz * it;
                if (tm[o]     != 0.0f) mse += e0 * e0;
                if (tm[o + 1] != 0.0f) mse += e1 * e1;
                if (tm[o + 2] != 0.0f) mse += e2 * e2;
            }
        }
        __syncthreads();   // protect s_pm/s_tm before next tile's writes
    }

    // ---- Block reduction (double), NO global atomics ----
    double v0 = (double)l1;
    double v1 = (double)mse;
    for (int off = 32; off > 0; off >>= 1) {
        v0 += __shfl_down(v0, off, 64);
        v1 += __shfl_down(v1, off, 64);
    }
    __shared__ double s_red0[THREADS / 64];
    __shared__ double s_red1[THREADS / 64];
    const int wave = tid >> 6;
    const int lane = tid & 63;
    if (lane == 0) { s_red0[wave] = v0; s_red1[wave] = v1; }
    __syncthreads();
    if (tid == 0) {
        part0[blockIdx.x] = s_red0[0] + s_red0[1] + s_red0[2] + s_red0[3];
        part1[blockIdx.x] = s_red1[0] + s_red1[1] + s_red1[2] + s_red1[3];
    }
}

__global__ __launch_bounds__(THREADS)
void loss_final(const double* __restrict__ part0,
                const double* __restrict__ part1,
                float* __restrict__ out)
{
    const int tid = threadIdx.x;
    double a = 0.0, b = 0.0;
    for (int i = tid; i < GRID_BLOCKS; i += THREADS) {
        a += part0[i];
        b += part1[i];
    }
    for (int off = 32; off > 0; off >>= 1) {
        a += __shfl_down(a, off, 64);
        b += __shfl_down(b, off, 64);
    }
    __shared__ double s0[THREADS / 64];
    __shared__ double s1[THREADS / 64];
    const int wave = tid >> 6;
    const int lane = tid & 63;
    if (lane == 0) { s0[wave] = a; s1[wave] = b; }
    __syncthreads();
    if (tid == 0) {
        double sa = s0[0] + s0[1] + s0[2] + s0[3];
        double sb = s1[0] + s1[1] + s1[2] + s1[3];
        const double N = 64.0 * 4096.0 * 150.0;  // both means over B*T*150
        out[0] = (float)(sa / N + 0.1 * (sb / N));
    }
}

extern "C" void kernel_launch(void* const* d_in, const int* in_sizes, int n_in,
                              void* d_out, int out_size, void* d_ws, size_t ws_size,
                              hipStream_t stream)
{
    (void)in_sizes; (void)n_in; (void)out_size; (void)ws_size;
    const float* preds   = (const float*)d_in[0];
    const float* targets = (const float*)d_in[1];
    double* part0 = (double*)d_ws;
    double* part1 = part0 + GRID_BLOCKS;   // 16 KB total in d_ws

    loss_main<<<GRID_BLOCKS, THREADS, 0, stream>>>(preds, targets, part0, part1);
    loss_final<<<1, THREADS, 0, stream>>>(part0, part1, (float*)d_out);
}

// Round 4
// 323.938 us; speedup vs baseline: 2.1297x; 1.0029x over previous
//
#include <hip/hip_runtime.h>

#define NUM_BONES  50
#define FEAT       150
#define FRAMES_PER_BLOCK 32
#define THREADS    256
#define TILE_ELEMS (FRAMES_PER_BLOCK * FEAT)   // 4800 floats per tensor
#define N4         (TILE_ELEMS / 4)            // 1200 float4s
#define NLOAD      5                           // ceil(1200/256)
#define TOTAL_TILES      ((64 * 4096) / FRAMES_PER_BLOCK)   // 8192
#define GRID_BLOCKS      1024                               // 4 blocks/CU (LDS-capped)
#define TILES_PER_BLOCK  (TOTAL_TILES / GRID_BLOCKS)        // 8

// 50-bone skeleton (body + two 21-bone hands + pad bone (0,2))
__device__ __constant__ int c_ba[NUM_BONES] = {
    0, 1, 2, 3, 1, 5, 6,
    7, 8, 9, 10, 11, 8, 13, 14, 15, 8, 17, 18, 19,
    8, 21, 22, 23, 8, 25, 26, 27,
    4, 29, 30, 31, 32, 29, 34, 35, 36, 29, 38, 39, 40,
    29, 42, 43, 44, 29, 46, 47, 48,
    0
};
__device__ __constant__ int c_bb[NUM_BONES] = {
    1, 2, 3, 4, 5, 6, 7,
    8, 9, 10, 11, 12, 13, 14, 15, 16, 17, 18, 19, 20,
    21, 22, 23, 24, 25, 26, 27, 28,
    29, 30, 31, 32, 33, 34, 35, 36, 37, 38, 39, 40, 41,
    42, 43, 44, 45, 46, 47, 48, 49,
    2
};

__global__ __launch_bounds__(THREADS)
void loss_main(const float* __restrict__ preds,
               const float* __restrict__ targets,
               double* __restrict__ part0,   // [GRID_BLOCKS] l1 partials
               double* __restrict__ part1)   // [GRID_BLOCKS] mse partials
{
    __shared__ float s_pm[TILE_ELEMS];
    __shared__ float s_tm[TILE_ELEMS];

    const int tid = threadIdx.x;
    float l1  = 0.0f;
    float mse = 0.0f;

    const float4* pbase = (const float4*)preds;
    const float4* tbase = (const float4*)targets;
    float4* spm4 = (float4*)s_pm;
    float4* stm4 = (float4*)s_tm;

    // Clamped per-thread load indices (branch-free, all loads unconditional)
    int idx[NLOAD];
#pragma unroll
    for (int k = 0; k < NLOAD; ++k) {
        int i = tid + k * THREADS;
        idx[k] = (i < N4) ? i : (N4 - 1);
    }

    // ---- Prologue: load tile 0 into registers ----
    float4 pr[NLOAD], tr[NLOAD];
    {
        const long long t0 = (long long)blockIdx.x * N4;
#pragma unroll
        for (int k = 0; k < NLOAD; ++k) {
            pr[k] = pbase[t0 + idx[k]];
            tr[k] = tbase[t0 + idx[k]];
        }
    }

#pragma unroll 1
    for (int j = 0; j < TILES_PER_BLOCK; ++j) {
        // ---- Stage current tile regs -> LDS, accumulate L1 ----
#pragma unroll
        for (int k = 0; k < NLOAD; ++k) {
            int i = tid + k * THREADS;
            if (i < N4) {
                float4 p = pr[k];
                float4 t = tr[k];
                float4 pm;
                // tm == t always: where t==0, t*m == 0 == t.
                pm.x = (t.x != 0.0f) ? p.x : 0.0f;
                pm.y = (t.y != 0.0f) ? p.y : 0.0f;
                pm.z = (t.z != 0.0f) ? p.z : 0.0f;
                pm.w = (t.w != 0.0f) ? p.w : 0.0f;
                l1 += fabsf(pm.x - t.x) + fabsf(pm.y - t.y)
                    + fabsf(pm.z - t.z) + fabsf(pm.w - t.w);
                spm4[i] = pm;
                stm4[i] = t;
            }
        }
        __syncthreads();

        // ---- Prefetch next tile into registers (hidden under phase 2) ----
        if (j + 1 < TILES_PER_BLOCK) {
            const long long tn =
                (long long)(blockIdx.x + (j + 1) * GRID_BLOCKS) * N4;
#pragma unroll
            for (int k = 0; k < NLOAD; ++k) {
                pr[k] = pbase[tn + idx[k]];
                tr[k] = tbase[tn + idx[k]];
            }
        }

        // ---- Phase 2: bone directions + masked MSE (reads LDS only) ----
        // f = i&31 (frame), b = i>>5 (bone): bone index uniform per half-wave
        // (scalar c_ba/c_bb); lane LDS stride = 150 words -> 2-way bank
        // aliasing across 32 lanes (free on gfx950, m136).
        const int ntask = FRAMES_PER_BLOCK * NUM_BONES;  // 1600
#pragma unroll
        for (int k = 0; k < 7; ++k) {
            const int i = tid + k * THREADS;
            if (i < ntask) {
                const int f = i & 31;
                const int b = i >> 5;
                const float* pm = s_pm + f * FEAT;
                const float* tm = s_tm + f * FEAT;
                const int ja = 3 * c_ba[b];
                const int jb = 3 * c_bb[b];

                float dpx = pm[ja]     - pm[jb];
                float dpy = pm[ja + 1] - pm[jb + 1];
                float dpz = pm[ja + 2] - pm[jb + 2];
                float dtx = tm[ja]     - tm[jb];
                float dty = tm[ja + 1] - tm[jb + 1];
                float dtz = tm[ja + 2] - tm[jb + 2];

                // dir = diff * rsqrt(|diff|^2); exact 0 when diff == 0.
                // rsq approx err ~1e-7 vs 2.4e-2 tolerance.
                float lp2 = dpx * dpx + dpy * dpy + dpz * dpz;
                float lt2 = dtx * dtx + dty * dty + dtz * dtz;
                float ip = (lp2 > 0.0f) ? __builtin_amdgcn_rsqf(lp2) : 0.0f;
                float it = (lt2 > 0.0f) ? __builtin_amdgcn_rsqf(lt2) : 0.0f;

                const int o = 3 * b;
                float e0 = dpx * ip - dtx * it;
                float e1 = dpy * ip - dty * it;
                float e2 = dpz * ip - dtz * it;
                mse += (tm[o]     != 0.0f) ? e0 * e0 : 0.0f;
                mse += (tm[o + 1] != 0.0f) ? e1 * e1 : 0.0f;
                mse += (tm[o + 2] != 0.0f) ? e2 * e2 : 0.0f;
            }
        }
        __syncthreads();   // protect s_pm/s_tm before next tile's writes
    }

    // ---- Block reduction (double), no global atomics ----
    double v0 = (double)l1;
    double v1 = (double)mse;
    for (int off = 32; off > 0; off >>= 1) {
        v0 += __shfl_down(v0, off, 64);
        v1 += __shfl_down(v1, off, 64);
    }
    __shared__ double s_red0[THREADS / 64];
    __shared__ double s_red1[THREADS / 64];
    const int wave = tid >> 6;
    const int lane = tid & 63;
    if (lane == 0) { s_red0[wave] = v0; s_red1[wave] = v1; }
    __syncthreads();
    if (tid == 0) {
        part0[blockIdx.x] = s_red0[0] + s_red0[1] + s_red0[2] + s_red0[3];
        part1[blockIdx.x] = s_red1[0] + s_red1[1] + s_red1[2] + s_red1[3];
    }
}

__global__ __launch_bounds__(THREADS)
void loss_final(const double* __restrict__ part0,
                const double* __restrict__ part1,
                float* __restrict__ out)
{
    const int tid = threadIdx.x;
    double a = 0.0, b = 0.0;
    for (int i = tid; i < GRID_BLOCKS; i += THREADS) {
        a += part0[i];
        b += part1[i];
    }
    for (int off = 32; off > 0; off >>= 1) {
        a += __shfl_down(a, off, 64);
        b += __shfl_down(b, off, 64);
    }
    __shared__ double s0[THREADS / 64];
    __shared__ double s1[THREADS / 64];
    const int wave = tid >> 6;
    const int lane = tid & 63;
    if (lane == 0) { s0[wave] = a; s1[wave] = b; }
    __syncthreads();
    if (tid == 0) {
        double sa = s0[0] + s0[1] + s0[2] + s0[3];
        double sb = s1[0] + s1[1] + s1[2] + s1[3];
        const double N = 64.0 * 4096.0 * 150.0;  // both means over B*T*150
        out[0] = (float)(sa / N + 0.1 * (sb / N));
    }
}

extern "C" void kernel_launch(void* const* d_in, const int* in_sizes, int n_in,
                              void* d_out, int out_size, void* d_ws, size_t ws_size,
                              hipStream_t stream)
{
    (void)in_sizes; (void)n_in; (void)out_size; (void)ws_size;
    const float* preds   = (const float*)d_in[0];
    const float* targets = (const float*)d_in[1];
    double* part0 = (double*)d_ws;
    double* part1 = part0 + GRID_BLOCKS;   // 16 KB total in d_ws

    loss_main<<<GRID_BLOCKS, THREADS, 0, stream>>>(preds, targets, part0, part1);
    loss_final<<<1, THREADS, 0, stream>>>(part0, part1, (float*)d_out);
}